// Round 1
// baseline (433.854 us; speedup 1.0000x reference)
//
#include <hip/hip_runtime.h>
#include <hip/hip_bf16.h>
#include <stdint.h>

#define TT 2048
#define NH 32
#define HD 64
#define HIDDEN 2048

typedef __attribute__((ext_vector_type(8))) short short8;
typedef __attribute__((ext_vector_type(4))) short short4v;
typedef __attribute__((ext_vector_type(4))) float f32x4;

__device__ inline short f2bf(float x) {
  __hip_bfloat16 h = __float2bfloat16(x);
  return __builtin_bit_cast(short, h);
}

__device__ inline void gload16(const void* g, void* l) {
  __builtin_amdgcn_global_load_lds(
      (const __attribute__((address_space(1))) unsigned int*)g,
      (__attribute__((address_space(3))) unsigned int*)l, 16, 0, 0);
}

// ---------------- cast fp32 -> bf16 (vectorized) ----------------
__global__ void cast_bf16(const float* __restrict__ src, short* __restrict__ dst, int n) {
  int idx = blockIdx.x * 256 + threadIdx.x;
  int i = idx * 4;
  if (i < n) {
    float4 v = *reinterpret_cast<const float4*>(src + i);
    short4v o;
    o[0] = f2bf(v.x); o[1] = f2bf(v.y); o[2] = f2bf(v.z); o[3] = f2bf(v.w);
    *reinterpret_cast<short4v*>(dst + i) = o;
  }
}

// ---------------- RoPE cos/sin table: rt[t*32+i] = (cos, sin) ----------------
__global__ void rope_table_kernel(float2* __restrict__ rt) {
  int idx = blockIdx.x * 256 + threadIdx.x;  // t*32 + i
  int t = idx >> 5, i = idx & 31;
  double inv = pow(10000.0, -(double)i / 32.0);
  float f = (float)t * (float)inv;
  float2 cs; cs.x = cosf(f); cs.y = sinf(f);
  rt[idx] = cs;
}

// ---------------- gk = log_sigmoid(hidden @ Wgk^T)/16, stored [h][t] fp32 ----
__global__ __launch_bounds__(256) void gk_kernel(const float* __restrict__ hidden,
                                                 const float* __restrict__ Wgk,
                                                 float* __restrict__ gk) {
  int t = blockIdx.x;
  __shared__ float row[HIDDEN];
  int tid = threadIdx.x;
  const float4* hr = reinterpret_cast<const float4*>(hidden + (size_t)t * HIDDEN);
#pragma unroll
  for (int i = 0; i < 2; i++) {
    float4 v = hr[tid + i * 256];
    *reinterpret_cast<float4*>(&row[(tid + i * 256) * 4]) = v;
  }
  __syncthreads();
  int w = tid >> 6, l = tid & 63;
  for (int hh = 0; hh < 8; hh++) {
    int h = w * 8 + hh;
    const float* wr = Wgk + (size_t)h * HIDDEN;
    float acc = 0.f;
#pragma unroll
    for (int i = 0; i < 32; i++) acc = fmaf(row[i * 64 + l], wr[i * 64 + l], acc);
#pragma unroll
    for (int m = 1; m < 64; m <<= 1) acc += __shfl_xor(acc, m, 64);
    if (l == 0) {
      float x = acc;
      float ls = fminf(x, 0.f) - log1pf(__expf(-fabsf(x)));
      gk[(size_t)h * TT + t] = ls * (1.0f / 16.0f);
    }
  }
}

// ---------------- per-head inclusive cumsum over t: G[h][t] ----------------
__global__ void cumsum_kernel(const float* __restrict__ gk, float* __restrict__ G) {
  int h = blockIdx.x;
  int l = threadIdx.x;  // 64 threads
  float carry = 0.f;
  for (int c = 0; c < 32; c++) {
    float x = gk[(size_t)h * TT + c * 64 + l];
#pragma unroll
    for (int ofs = 1; ofs < 64; ofs <<= 1) {
      float y = __shfl_up(x, ofs, 64);
      if (l >= ofs) x += y;
    }
    x += carry;
    G[(size_t)h * TT + c * 64 + l] = x;
    carry = __shfl(x, 63, 64);
  }
}

// ---------------- m97-style bf16 GEMM: C[M][N] = A[M][K] * B[N][K]^T --------
// A, B bf16 (short bits), C fp32. M,N multiples of 128; K multiple of 32.
__global__ __launch_bounds__(256) void gemm_bt(const short* __restrict__ A,
                                               const short* __restrict__ B,
                                               float* __restrict__ C,
                                               int M, int N, int K) {
  __shared__ short As[128 * 32];
  __shared__ short Bs[128 * 32];
  int tm = blockIdx.y * 128;
  int tn = blockIdx.x * 128;
  int tid = threadIdx.x;
  int w = tid >> 6, l = tid & 63;
  int wr = w >> 1, wc = w & 1;
  int srow = l >> 2;          // 0..15
  int scol = (l & 3) * 8;     // k-element offset of 16B chunk
  int lg = l >> 4, lr = l & 15;
  f32x4 acc[4][4] = {};
  for (int k0 = 0; k0 < K; k0 += 32) {
    __syncthreads();
#pragma unroll
    for (int i = 0; i < 2; i++) {
      int r = i * 64 + w * 16 + srow;
      gload16(A + (size_t)(tm + r) * K + k0 + scol, &As[(i * 64 + w * 16) * 32]);
      gload16(B + (size_t)(tn + r) * K + k0 + scol, &Bs[(i * 64 + w * 16) * 32]);
    }
    __syncthreads();
    short8 a[4], b[4];
#pragma unroll
    for (int m = 0; m < 4; m++)
      a[m] = *reinterpret_cast<const short8*>(&As[(wr * 64 + m * 16 + lr) * 32 + lg * 8]);
#pragma unroll
    for (int n = 0; n < 4; n++)
      b[n] = *reinterpret_cast<const short8*>(&Bs[(wc * 64 + n * 16 + lr) * 32 + lg * 8]);
#pragma unroll
    for (int m = 0; m < 4; m++)
#pragma unroll
      for (int n = 0; n < 4; n++)
        acc[m][n] = __builtin_amdgcn_mfma_f32_16x16x32_bf16(a[m], b[n], acc[m][n], 0, 0, 0);
  }
#pragma unroll
  for (int m = 0; m < 4; m++)
#pragma unroll
    for (int n = 0; n < 4; n++)
#pragma unroll
      for (int r = 0; r < 4; r++) {
        int row = tm + wr * 64 + m * 16 + lg * 4 + r;
        int col = tn + wc * 64 + n * 16 + lr;
        C[(size_t)row * N + col] = acc[m][n][r];
      }
}

// ---------------- RoPE post-pass + layout conversion -------------------------
// QKVG fp32 [T][8192]: cols 0-2047 q, 2048-4095 k, 4096-6143 v, 6144-8191 g.
// Writes qb[h][t][d], kb[h][t][d] (bf16, RoPE'd) and vtb[h][d][t] (bf16).
__global__ __launch_bounds__(256) void rope_post(const float* __restrict__ QKVG,
                                                 const float2* __restrict__ rt,
                                                 short* __restrict__ qb,
                                                 short* __restrict__ kb,
                                                 short* __restrict__ vtb) {
  int tb = blockIdx.x, h = blockIdx.y;
  int tid = threadIdx.x;
  int p = tid & 31;    // pair index 0..31
  int r0 = tid >> 5;   // 0..7
#pragma unroll
  for (int rr = 0; rr < 8; rr++) {
    int rloc = r0 * 8 + rr;
    int t = tb * 64 + rloc;
    float2 cs = rt[(size_t)t * 32 + p];
    // q
    float2 xq = *reinterpret_cast<const float2*>(&QKVG[(size_t)t * 8192 + h * 64 + 2 * p]);
    float r1 = xq.x * cs.x - xq.y * cs.y;
    float r2 = xq.x * cs.y + xq.y * cs.x;
    short4v dummy;
    ushort2 uq; uq.x = (unsigned short)f2bf(r1); uq.y = (unsigned short)f2bf(r2);
    *reinterpret_cast<ushort2*>(&qb[((size_t)h * TT + t) * 64 + 2 * p]) = uq;
    // k
    float2 xk = *reinterpret_cast<const float2*>(&QKVG[(size_t)t * 8192 + 2048 + h * 64 + 2 * p]);
    r1 = xk.x * cs.x - xk.y * cs.y;
    r2 = xk.x * cs.y + xk.y * cs.x;
    ushort2 uk; uk.x = (unsigned short)f2bf(r1); uk.y = (unsigned short)f2bf(r2);
    *reinterpret_cast<ushort2*>(&kb[((size_t)h * TT + t) * 64 + 2 * p]) = uk;
  }
  // v transpose via LDS (fp32 [64][65] -> conflict-free column read)
  __shared__ float vt[64][65];
  int c = tid & 63;
  int rbase = tid >> 6;  // 0..3
#pragma unroll
  for (int k4 = 0; k4 < 16; k4++) {
    int rloc = rbase * 16 + k4;
    vt[rloc][c] = QKVG[(size_t)(tb * 64 + rloc) * 8192 + 4096 + h * 64 + c];
  }
  __syncthreads();
#pragma unroll
  for (int k4 = 0; k4 < 16; k4++) {
    int d = rbase * 16 + k4;
    float val = vt[c][d];
    vtb[((size_t)h * HD + d) * TT + tb * 64 + c] = f2bf(val);
  }
}

// ---------------- gated-retention attention ---------------------------------
// grid: (qblk=32, h=32), 256 threads (4 waves x 16 query rows).
// o[t][h][:] = sum_{j<=t} exp(G_t - G_j) * 0.125 * (q_t . k_j) * v_j
// then RMS-norm over d, * silu(g), write z bf16 [t][2048].
__global__ __launch_bounds__(256) void attn_kernel(const short* __restrict__ qbuf,
                                                   const short* __restrict__ kbuf,
                                                   const short* __restrict__ vtbuf,
                                                   const float* __restrict__ G,
                                                   const float* __restrict__ QKVG,
                                                   short* __restrict__ z) {
  int qblk = blockIdx.x, h = blockIdx.y;
  __shared__ short Ks[64 * 64];   // [j][d], XOR-swizzled rows
  __shared__ short Vs[64 * 64];   // [d][j], XOR-swizzled rows
  __shared__ short Ps[4][16 * 64];
  int tid = threadIdx.x, w = tid >> 6, l = tid & 63;
  int lg = l >> 4, lr = l & 15;

  // Q A-frags (held in regs across j-blocks)
  int tq_row = qblk * 64 + w * 16 + lr;
  short8 aq0 = *reinterpret_cast<const short8*>(&qbuf[((size_t)h * TT + tq_row) * HD + lg * 8]);
  short8 aq1 = *reinterpret_cast<const short8*>(&qbuf[((size_t)h * TT + tq_row) * HD + 32 + lg * 8]);

  // G for this wave's accumulator rows (D-frag layout rows)
  int tq0 = qblk * 64 + w * 16 + lg * 4;
  float Gq[4];
#pragma unroll
  for (int r = 0; r < 4; r++) Gq[r] = G[(size_t)h * TT + tq0 + r];

  f32x4 o[4] = {};
  int sj = w * 8 + (l >> 3);  // staging row within half-tile

  for (int jb = 0; jb <= qblk; jb++) {
    __syncthreads();
#pragma unroll
    for (int i = 0; i < 2; i++) {
      int row = i * 32 + sj;
      int cb = ((l & 7) ^ (row & 7)) * 8;  // pre-swizzled source column (elements)
      gload16(&kbuf[((size_t)h * TT + jb * 64 + row) * HD + cb], &Ks[(i * 32 + w * 8) * 64]);
      gload16(&vtbuf[((size_t)h * HD + row) * TT + jb * 64 + cb], &Vs[(i * 32 + w * 8) * 64]);
    }
    __syncthreads();

    // S = Q K^T  (16x64 per wave), decay+mask, P -> per-wave LDS strip
#pragma unroll
    for (int n = 0; n < 4; n++) {
      int j = n * 16 + lr;
      short8 bk0 = *reinterpret_cast<const short8*>((const char*)Ks + j * 128 + ((lg * 16) ^ ((j & 7) << 4)));
      short8 bk1 = *reinterpret_cast<const short8*>((const char*)Ks + j * 128 + ((64 + lg * 16) ^ ((j & 7) << 4)));
      f32x4 s = {};
      s = __builtin_amdgcn_mfma_f32_16x16x32_bf16(aq0, bk0, s, 0, 0, 0);
      s = __builtin_amdgcn_mfma_f32_16x16x32_bf16(aq1, bk1, s, 0, 0, 0);
      int tj = jb * 64 + n * 16 + lr;
      float Gk = G[(size_t)h * TT + tj];
#pragma unroll
      for (int r = 0; r < 4; r++) {
        int tq = tq0 + r;
        float pv = 0.f;
        if (tj <= tq) pv = __expf(Gq[r] - Gk) * 0.125f * s[r];
        int qloc = lg * 4 + r;
        int jloc = n * 16 + lr;
        int boff = qloc * 128 + ((jloc * 2) ^ ((qloc & 7) << 4));
        *reinterpret_cast<short*>((char*)&Ps[w][0] + boff) = f2bf(pv);
      }
    }

    // PV: O += P * V   (LDS ops within a wave are in-order -> no barrier needed)
    short8 pa0 = *reinterpret_cast<const short8*>((const char*)&Ps[w][0] + lr * 128 + ((lg * 16) ^ ((lr & 7) << 4)));
    short8 pa1 = *reinterpret_cast<const short8*>((const char*)&Ps[w][0] + lr * 128 + ((64 + lg * 16) ^ ((lr & 7) << 4)));
#pragma unroll
    for (int n = 0; n < 4; n++) {
      int d = n * 16 + lr;
      short8 bv0 = *reinterpret_cast<const short8*>((const char*)Vs + d * 128 + ((lg * 16) ^ ((d & 7) << 4)));
      short8 bv1 = *reinterpret_cast<const short8*>((const char*)Vs + d * 128 + ((64 + lg * 16) ^ ((d & 7) << 4)));
      o[n] = __builtin_amdgcn_mfma_f32_16x16x32_bf16(pa0, bv0, o[n], 0, 0, 0);
      o[n] = __builtin_amdgcn_mfma_f32_16x16x32_bf16(pa1, bv1, o[n], 0, 0, 0);
    }
  }

  // epilogue: RMS-norm over d=64, * silu(gate), store bf16
  float sums[4];
#pragma unroll
  for (int r = 0; r < 4; r++) {
    float ss = 0.f;
#pragma unroll
    for (int n = 0; n < 4; n++) ss += o[n][r] * o[n][r];
#pragma unroll
    for (int m = 1; m < 16; m <<= 1) ss += __shfl_xor(ss, m, 64);
    sums[r] = ss;
  }
#pragma unroll
  for (int r = 0; r < 4; r++) {
    int tq = tq0 + r;
    float rstd = rsqrtf(sums[r] * (1.0f / 64.0f) + 1e-6f);
#pragma unroll
    for (int n = 0; n < 4; n++) {
      int d = n * 16 + lr;
      float gv = QKVG[(size_t)tq * 8192 + 6144 + h * 64 + d];
      float sg = gv / (1.0f + __expf(-gv));
      float val = o[n][r] * rstd * sg;
      z[(size_t)tq * HIDDEN + h * 64 + d] = f2bf(val);
    }
  }
}

// ---------------- launch ----------------
extern "C" void kernel_launch(void* const* d_in, const int* in_sizes, int n_in,
                              void* d_out, int out_size, void* d_ws, size_t ws_size,
                              hipStream_t stream) {
  const float* hidden = (const float*)d_in[0];
  const float* Wq = (const float*)d_in[1];
  const float* Wk = (const float*)d_in[2];
  const float* Wv = (const float*)d_in[3];
  const float* Wg = (const float*)d_in[4];
  const float* Wgk = (const float*)d_in[5];
  const float* Wo = (const float*)d_in[6];
  float* out = (float*)d_out;
  char* ws = (char*)d_ws;

  const size_t NELEM = (size_t)TT * HIDDEN;            // 4M
  short* XbZ  = (short*)(ws + 0);                      // 8MB  (Xb, later reused as z)
  short* Wb   = (short*)(ws + 8388608);                // 32MB (packed Wq|Wk|Wv|Wg)
  short* Wob  = (short*)(ws + 41943040);               // 8MB
  float* QKVG = (float*)(ws + 50331648);               // 64MB
  short* qbuf = (short*)(ws + 117440512);              // 8MB
  short* kbuf = (short*)(ws + 125829120);              // 8MB
  short* vtbuf= (short*)(ws + 134217728);              // 8MB
  float* gkb  = (float*)(ws + 142606336);              // 256KB
  float* Gb   = (float*)(ws + 142868480);              // 256KB
  float2* rt  = (float2*)(ws + 143130624);             // 512KB

  int nblk = (int)(NELEM / 4 / 256);
  cast_bf16<<<nblk, 256, 0, stream>>>(hidden, XbZ, (int)NELEM);
  cast_bf16<<<nblk, 256, 0, stream>>>(Wq, Wb + 0 * NELEM, (int)NELEM);
  cast_bf16<<<nblk, 256, 0, stream>>>(Wk, Wb + 1 * NELEM, (int)NELEM);
  cast_bf16<<<nblk, 256, 0, stream>>>(Wv, Wb + 2 * NELEM, (int)NELEM);
  cast_bf16<<<nblk, 256, 0, stream>>>(Wg, Wb + 3 * NELEM, (int)NELEM);
  cast_bf16<<<nblk, 256, 0, stream>>>(Wo, Wob, (int)NELEM);
  rope_table_kernel<<<256, 256, 0, stream>>>(rt);
  gk_kernel<<<TT, 256, 0, stream>>>(hidden, Wgk, gkb);
  cumsum_kernel<<<NH, 64, 0, stream>>>(gkb, Gb);
  gemm_bt<<<dim3(64, 16), 256, 0, stream>>>(XbZ, Wb, QKVG, TT, 4 * HIDDEN, HIDDEN);
  rope_post<<<dim3(32, NH), 256, 0, stream>>>(QKVG, rt, qbuf, kbuf, vtbuf);
  attn_kernel<<<dim3(32, NH), 256, 0, stream>>>(qbuf, kbuf, vtbuf, Gb, QKVG, XbZ);
  gemm_bt<<<dim3(16, 16), 256, 0, stream>>>(XbZ, Wob, out, TT, HIDDEN, HIDDEN);
}

// Round 7
// 394.505 us; speedup vs baseline: 1.0997x; 1.0997x over previous
//
#include <hip/hip_runtime.h>
#include <hip/hip_bf16.h>
#include <stdint.h>

#define TT 2048
#define NH 32
#define HD 64
#define HIDDEN 2048

typedef __attribute__((ext_vector_type(8))) short short8;
typedef __attribute__((ext_vector_type(4))) short short4v;
typedef __attribute__((ext_vector_type(4))) float f32x4;

__device__ inline short f2bf(float x) {
  __hip_bfloat16 h = __float2bfloat16(x);
  return __builtin_bit_cast(short, h);
}

__device__ inline void gload16(const void* g, void* l) {
  __builtin_amdgcn_global_load_lds(
      (const __attribute__((address_space(1))) unsigned int*)g,
      (__attribute__((address_space(3))) unsigned int*)l, 16, 0, 0);
}

// ---------------- fused fp32 -> bf16 casts (6 buffers of 4M elems) ----------
__global__ void cast6(const float* __restrict__ s0, const float* __restrict__ s1,
                      const float* __restrict__ s2, const float* __restrict__ s3,
                      const float* __restrict__ s4, const float* __restrict__ s5,
                      short* __restrict__ d0, short* __restrict__ d1,
                      short* __restrict__ d2, short* __restrict__ d3,
                      short* __restrict__ d4, short* __restrict__ d5) {
  int t0 = blockIdx.x * 256 + threadIdx.x;
  int stride = gridDim.x * 256;
  const int NG = 1 << 20;  // 4M elems / 4 per thread
#define CAST_LOOP(S, D)                                            \
  for (int g = t0; g < NG; g += stride) {                          \
    float4 v = *reinterpret_cast<const float4*>(S + (size_t)g * 4);\
    short4v o;                                                     \
    o[0] = f2bf(v.x); o[1] = f2bf(v.y);                            \
    o[2] = f2bf(v.z); o[3] = f2bf(v.w);                            \
    *reinterpret_cast<short4v*>(D + (size_t)g * 4) = o;            \
  }
  CAST_LOOP(s0, d0)
  CAST_LOOP(s1, d1)
  CAST_LOOP(s2, d2)
  CAST_LOOP(s3, d3)
  CAST_LOOP(s4, d4)
  CAST_LOOP(s5, d5)
#undef CAST_LOOP
}

// ---------------- RoPE cos/sin table: rt[t*32+i] = (cos, sin) ----------------
__global__ void rope_table_kernel(float2* __restrict__ rt) {
  int idx = blockIdx.x * 256 + threadIdx.x;  // t*32 + i
  int t = idx >> 5, i = idx & 31;
  // inv_freq = 10000^(-i/32) = exp2(-i * log2(10000)/32)
  float inv = exp2f(-(float)i * (13.287712379549449f / 32.0f));
  float f = (float)t * inv;
  float2 cs; cs.x = cosf(f); cs.y = sinf(f);
  rt[idx] = cs;
}

// ---------------- gk = log_sigmoid(hidden @ Wgk^T)/16, stored [h][t] fp32 ----
__global__ __launch_bounds__(256) void gk_kernel(const float* __restrict__ hidden,
                                                 const float* __restrict__ Wgk,
                                                 float* __restrict__ gk) {
  int t = blockIdx.x;
  __shared__ float row[HIDDEN];
  int tid = threadIdx.x;
  const float4* hr = reinterpret_cast<const float4*>(hidden + (size_t)t * HIDDEN);
#pragma unroll
  for (int i = 0; i < 2; i++) {
    float4 v = hr[tid + i * 256];
    *reinterpret_cast<float4*>(&row[(tid + i * 256) * 4]) = v;
  }
  __syncthreads();
  int w = tid >> 6, l = tid & 63;
  for (int hh = 0; hh < 8; hh++) {
    int h = w * 8 + hh;
    const float* wr = Wgk + (size_t)h * HIDDEN;
    float acc = 0.f;
#pragma unroll
    for (int i = 0; i < 32; i++) acc = fmaf(row[i * 64 + l], wr[i * 64 + l], acc);
#pragma unroll
    for (int m = 1; m < 64; m <<= 1) acc += __shfl_xor(acc, m, 64);
    if (l == 0) {
      float x = acc;
      float ls = fminf(x, 0.f) - log1pf(__expf(-fabsf(x)));
      gk[(size_t)h * TT + t] = ls * (1.0f / 16.0f);
    }
  }
}

// ---------------- per-head inclusive cumsum over t: G[h][t] ----------------
__global__ void cumsum_kernel(const float* __restrict__ gk, float* __restrict__ G) {
  int h = blockIdx.x;
  int l = threadIdx.x;  // 64 threads
  float carry = 0.f;
  for (int c = 0; c < 32; c++) {
    float x = gk[(size_t)h * TT + c * 64 + l];
#pragma unroll
    for (int ofs = 1; ofs < 64; ofs <<= 1) {
      float y = __shfl_up(x, ofs, 64);
      if (l >= ofs) x += y;
    }
    x += carry;
    G[(size_t)h * TT + c * 64 + l] = x;
    carry = __shfl(x, 63, 64);
  }
}

// ---------------- 256x256 deep-pipelined bf16 GEMM: C = A * B^T --------------
// A[M][K], B[N][K] bf16; C[M][N] fp32. M,N mult of 256; K mult of 32, K/32>=3.
// 512 threads = 8 waves (2 wr x 4 wc), per-wave 128x64 output, acc[8][4].
// LDS: 4-slot ring of K-tiles (BK=32): slot = 16KB A + 16KB B = 32KB, 128KB tot.
// Stage tile t+3 while computing tile t (slot (t+3)&3 == (t-1)&3, freed at the
// previous boundary). vmcnt(8) at tile boundary == "2 younger tiles (4 loads
// each) may be outstanding" => tile t+1 is resident. Never drains to 0 in loop.
__global__ __launch_bounds__(512, 1) void gemm256(const short* __restrict__ A,
                                                  const short* __restrict__ B,
                                                  float* __restrict__ C,
                                                  int M, int N, int K) {
  __shared__ short lds[4 * 16384];  // [slot][A:8192 | B:8192] shorts
  int tid = threadIdx.x;
  int w = tid >> 6, l = tid & 63;
  int wr = w >> 2, wc = w & 3;
  int lr = l & 15, lg = l >> 4;

  // block tile with XCD column-stripe swizzle (bijective when gridDim.x%8==0)
  int bx = blockIdx.x, by = blockIdx.y;
  if ((gridDim.x & 7) == 0) {
    int id = by * gridDim.x + bx;
    int sx = gridDim.x >> 3;
    int xcd = id & 7, p = id >> 3;
    bx = xcd * sx + p % sx;
    by = p / sx;
  }
  size_t tm = (size_t)by * 256, tn = (size_t)bx * 256;

  // stage source: lane covers row (w*16 + l/4 [+128*j]), phys chunk l&3.
  // pre-swizzled source chunk = (l&3) ^ s(row), s(row)=(row&3)^((row>>2)&3)
  int srow = l >> 2;
  int schunk = (((l & 3) ^ ((l >> 2) & 3) ^ ((l >> 4) & 3)) << 3);
  const short* pA0 = A + (size_t)(tm + w * 16 + srow) * K + schunk;
  const short* pA1 = A + (size_t)(tm + 128 + w * 16 + srow) * K + schunk;
  const short* pB0 = B + (size_t)(tn + w * 16 + srow) * K + schunk;
  const short* pB1 = B + (size_t)(tn + 128 + w * 16 + srow) * K + schunk;
  int dA0 = (0 * 128 + w * 16) * 32;          // LDS short offsets (wave-uniform)
  int dA1 = (1 * 128 + w * 16) * 32;
  int dB0 = 8192 + (0 * 128 + w * 16) * 32;
  int dB1 = 8192 + (1 * 128 + w * 16) * 32;

  // read offsets: frag row = base + i*16 + lr, chunk = lg ^ (lr&3) ^ ((lr>>2)&3)
  int rchunk = ((lg ^ ((lr & 3) ^ ((lr >> 2) & 3))) << 3);
  int baseA = (wr * 128 + lr) * 32 + rchunk;
  int baseB = (wc * 64 + lr) * 32 + rchunk;

  f32x4 acc[8][4] = {};
  int nt = K >> 5;

  // prologue: stage tiles 0,1,2 (12 loads); wait oldest 4 (tile 0) landed
  for (int t = 0; t < 3; ++t) {
    short* sb = &lds[(t & 3) * 16384];
    gload16(pA0 + (size_t)t * 32, sb + dA0);
    gload16(pA1 + (size_t)t * 32, sb + dA1);
    gload16(pB0 + (size_t)t * 32, sb + dB0);
    gload16(pB1 + (size_t)t * 32, sb + dB1);
  }
  asm volatile("s_waitcnt vmcnt(8)" ::: "memory");
  __builtin_amdgcn_s_barrier();

  for (int t = 0; t < nt; ++t) {
    const short* As = &lds[(t & 3) * 16384];
    const short* Bs = As + 8192;
    int pf = t + 3;
    bool do_pf = pf < nt;
    short* pfb = &lds[(pf & 3) * 16384];

    // ---- phase 0: read A(m0-3), B(n0-3); stage A of tile t+3; MFMA 16 ----
    short8 a[4], b[4];
#pragma unroll
    for (int mi = 0; mi < 4; mi++)
      a[mi] = *reinterpret_cast<const short8*>(As + baseA + mi * 512);
#pragma unroll
    for (int ni = 0; ni < 4; ni++)
      b[ni] = *reinterpret_cast<const short8*>(Bs + baseB + ni * 512);
    if (do_pf) {
      gload16(pA0 + (size_t)pf * 32, pfb + dA0);
      gload16(pA1 + (size_t)pf * 32, pfb + dA1);
    }
    __builtin_amdgcn_s_barrier();
    asm volatile("s_waitcnt lgkmcnt(0)" ::: "memory");
    __builtin_amdgcn_s_setprio(1);
#pragma unroll
    for (int mi = 0; mi < 4; mi++)
#pragma unroll
      for (int ni = 0; ni < 4; ni++)
        acc[mi][ni] = __builtin_amdgcn_mfma_f32_16x16x32_bf16(a[mi], b[ni], acc[mi][ni], 0, 0, 0);
    __builtin_amdgcn_s_setprio(0);
    __builtin_amdgcn_s_barrier();

    // ---- phase 1: read A(m4-7) (reuse B); stage B of tile t+3; MFMA 16 ----
#pragma unroll
    for (int mi = 0; mi < 4; mi++)
      a[mi] = *reinterpret_cast<const short8*>(As + baseA + (mi + 4) * 512);
    if (do_pf) {
      gload16(pB0 + (size_t)pf * 32, pfb + dB0);
      gload16(pB1 + (size_t)pf * 32, pfb + dB1);
    }
    __builtin_amdgcn_s_barrier();
    asm volatile("s_waitcnt lgkmcnt(0)" ::: "memory");
    __builtin_amdgcn_s_setprio(1);
#pragma unroll
    for (int mi = 0; mi < 4; mi++)
#pragma unroll
      for (int ni = 0; ni < 4; ni++)
        acc[mi + 4][ni] = __builtin_amdgcn_mfma_f32_16x16x32_bf16(a[mi], b[ni], acc[mi + 4][ni], 0, 0, 0);
    __builtin_amdgcn_s_setprio(0);
    // tile boundary: tile t+1 must be resident; allow tiles t+2,t+3 in flight
    asm volatile("s_waitcnt vmcnt(8)" ::: "memory");
    __builtin_amdgcn_s_barrier();
  }

#pragma unroll
  for (int mi = 0; mi < 8; mi++)
#pragma unroll
    for (int ni = 0; ni < 4; ni++)
#pragma unroll
      for (int r = 0; r < 4; r++) {
        size_t row = tm + wr * 128 + mi * 16 + lg * 4 + r;
        size_t col = tn + wc * 64 + ni * 16 + lr;
        C[row * N + col] = acc[mi][ni][r];
      }
}

// ---------------- m97-style bf16 GEMM (kept for the 2048x2048 out-proj) -----
__global__ __launch_bounds__(256) void gemm_bt(const short* __restrict__ A,
                                               const short* __restrict__ B,
                                               float* __restrict__ C,
                                               int M, int N, int K) {
  __shared__ short As[128 * 32];
  __shared__ short Bs[128 * 32];
  int tm = blockIdx.y * 128;
  int tn = blockIdx.x * 128;
  int tid = threadIdx.x;
  int w = tid >> 6, l = tid & 63;
  int wr = w >> 1, wc = w & 1;
  int srow = l >> 2;
  int scol = (l & 3) * 8;
  int lg = l >> 4, lr = l & 15;
  f32x4 acc[4][4] = {};
  for (int k0 = 0; k0 < K; k0 += 32) {
    __syncthreads();
#pragma unroll
    for (int i = 0; i < 2; i++) {
      int r = i * 64 + w * 16 + srow;
      gload16(A + (size_t)(tm + r) * K + k0 + scol, &As[(i * 64 + w * 16) * 32]);
      gload16(B + (size_t)(tn + r) * K + k0 + scol, &Bs[(i * 64 + w * 16) * 32]);
    }
    __syncthreads();
    short8 a[4], b[4];
#pragma unroll
    for (int m = 0; m < 4; m++)
      a[m] = *reinterpret_cast<const short8*>(&As[(wr * 64 + m * 16 + lr) * 32 + lg * 8]);
#pragma unroll
    for (int n = 0; n < 4; n++)
      b[n] = *reinterpret_cast<const short8*>(&Bs[(wc * 64 + n * 16 + lr) * 32 + lg * 8]);
#pragma unroll
    for (int m = 0; m < 4; m++)
#pragma unroll
      for (int n = 0; n < 4; n++)
        acc[m][n] = __builtin_amdgcn_mfma_f32_16x16x32_bf16(a[m], b[n], acc[m][n], 0, 0, 0);
  }
#pragma unroll
  for (int m = 0; m < 4; m++)
#pragma unroll
    for (int n = 0; n < 4; n++)
#pragma unroll
      for (int r = 0; r < 4; r++) {
        int row = tm + wr * 64 + m * 16 + lg * 4 + r;
        int col = tn + wc * 64 + n * 16 + lr;
        C[(size_t)row * N + col] = acc[m][n][r];
      }
}

// ---------------- RoPE post-pass + layout conversion -------------------------
__global__ __launch_bounds__(256) void rope_post(const float* __restrict__ QKVG,
                                                 const float2* __restrict__ rt,
                                                 short* __restrict__ qb,
                                                 short* __restrict__ kb,
                                                 short* __restrict__ vtb) {
  int tb = blockIdx.x, h = blockIdx.y;
  int tid = threadIdx.x;
  int p = tid & 31;
  int r0 = tid >> 5;
#pragma unroll
  for (int rr = 0; rr < 8; rr++) {
    int rloc = r0 * 8 + rr;
    int t = tb * 64 + rloc;
    float2 cs = rt[(size_t)t * 32 + p];
    float2 xq = *reinterpret_cast<const float2*>(&QKVG[(size_t)t * 8192 + h * 64 + 2 * p]);
    float r1 = xq.x * cs.x - xq.y * cs.y;
    float r2 = xq.x * cs.y + xq.y * cs.x;
    ushort2 uq; uq.x = (unsigned short)f2bf(r1); uq.y = (unsigned short)f2bf(r2);
    *reinterpret_cast<ushort2*>(&qb[((size_t)h * TT + t) * 64 + 2 * p]) = uq;
    float2 xk = *reinterpret_cast<const float2*>(&QKVG[(size_t)t * 8192 + 2048 + h * 64 + 2 * p]);
    r1 = xk.x * cs.x - xk.y * cs.y;
    r2 = xk.x * cs.y + xk.y * cs.x;
    ushort2 uk; uk.x = (unsigned short)f2bf(r1); uk.y = (unsigned short)f2bf(r2);
    *reinterpret_cast<ushort2*>(&kb[((size_t)h * TT + t) * 64 + 2 * p]) = uk;
  }
  __shared__ float vt[64][65];
  int c = tid & 63;
  int rbase = tid >> 6;
#pragma unroll
  for (int k4 = 0; k4 < 16; k4++) {
    int rloc = rbase * 16 + k4;
    vt[rloc][c] = QKVG[(size_t)(tb * 64 + rloc) * 8192 + 4096 + h * 64 + c];
  }
  __syncthreads();
#pragma unroll
  for (int k4 = 0; k4 < 16; k4++) {
    int d = rbase * 16 + k4;
    float val = vt[c][d];
    vtb[((size_t)h * HD + d) * TT + tb * 64 + c] = f2bf(val);
  }
}

// ---------------- gated-retention attention ---------------------------------
__global__ __launch_bounds__(256) void attn_kernel(const short* __restrict__ qbuf,
                                                   const short* __restrict__ kbuf,
                                                   const short* __restrict__ vtbuf,
                                                   const float* __restrict__ G,
                                                   const float* __restrict__ QKVG,
                                                   short* __restrict__ z) {
  int qblk = blockIdx.x, h = blockIdx.y;
  __shared__ short Ks[64 * 64];
  __shared__ short Vs[64 * 64];
  __shared__ short Ps[4][16 * 64];
  int tid = threadIdx.x, w = tid >> 6, l = tid & 63;
  int lg = l >> 4, lr = l & 15;

  int tq_row = qblk * 64 + w * 16 + lr;
  short8 aq0 = *reinterpret_cast<const short8*>(&qbuf[((size_t)h * TT + tq_row) * HD + lg * 8]);
  short8 aq1 = *reinterpret_cast<const short8*>(&qbuf[((size_t)h * TT + tq_row) * HD + 32 + lg * 8]);

  int tq0 = qblk * 64 + w * 16 + lg * 4;
  float Gq[4];
#pragma unroll
  for (int r = 0; r < 4; r++) Gq[r] = G[(size_t)h * TT + tq0 + r];

  f32x4 o[4] = {};
  int sj = w * 8 + (l >> 3);

  for (int jb = 0; jb <= qblk; jb++) {
    __syncthreads();
#pragma unroll
    for (int i = 0; i < 2; i++) {
      int row = i * 32 + sj;
      int cb = ((l & 7) ^ (row & 7)) * 8;
      gload16(&kbuf[((size_t)h * TT + jb * 64 + row) * HD + cb], &Ks[(i * 32 + w * 8) * 64]);
      gload16(&vtbuf[((size_t)h * HD + row) * TT + jb * 64 + cb], &Vs[(i * 32 + w * 8) * 64]);
    }
    __syncthreads();

#pragma unroll
    for (int n = 0; n < 4; n++) {
      int j = n * 16 + lr;
      short8 bk0 = *reinterpret_cast<const short8*>((const char*)Ks + j * 128 + ((lg * 16) ^ ((j & 7) << 4)));
      short8 bk1 = *reinterpret_cast<const short8*>((const char*)Ks + j * 128 + ((64 + lg * 16) ^ ((j & 7) << 4)));
      f32x4 s = {};
      s = __builtin_amdgcn_mfma_f32_16x16x32_bf16(aq0, bk0, s, 0, 0, 0);
      s = __builtin_amdgcn_mfma_f32_16x16x32_bf16(aq1, bk1, s, 0, 0, 0);
      int tj = jb * 64 + n * 16 + lr;
      float Gk = G[(size_t)h * TT + tj];
#pragma unroll
      for (int r = 0; r < 4; r++) {
        int tq = tq0 + r;
        float pv = 0.f;
        if (tj <= tq) pv = __expf(Gq[r] - Gk) * 0.125f * s[r];
        int qloc = lg * 4 + r;
        int jloc = n * 16 + lr;
        int boff = qloc * 128 + ((jloc * 2) ^ ((qloc & 7) << 4));
        *reinterpret_cast<short*>((char*)&Ps[w][0] + boff) = f2bf(pv);
      }
    }

    short8 pa0 = *reinterpret_cast<const short8*>((const char*)&Ps[w][0] + lr * 128 + ((lg * 16) ^ ((lr & 7) << 4)));
    short8 pa1 = *reinterpret_cast<const short8*>((const char*)&Ps[w][0] + lr * 128 + ((64 + lg * 16) ^ ((lr & 7) << 4)));
    __builtin_amdgcn_s_setprio(1);
#pragma unroll
    for (int n = 0; n < 4; n++) {
      int d = n * 16 + lr;
      short8 bv0 = *reinterpret_cast<const short8*>((const char*)Vs + d * 128 + ((lg * 16) ^ ((d & 7) << 4)));
      short8 bv1 = *reinterpret_cast<const short8*>((const char*)Vs + d * 128 + ((64 + lg * 16) ^ ((d & 7) << 4)));
      o[n] = __builtin_amdgcn_mfma_f32_16x16x32_bf16(pa0, bv0, o[n], 0, 0, 0);
      o[n] = __builtin_amdgcn_mfma_f32_16x16x32_bf16(pa1, bv1, o[n], 0, 0, 0);
    }
    __builtin_amdgcn_s_setprio(0);
  }

  float sums[4];
#pragma unroll
  for (int r = 0; r < 4; r++) {
    float ss = 0.f;
#pragma unroll
    for (int n = 0; n < 4; n++) ss += o[n][r] * o[n][r];
#pragma unroll
    for (int m = 1; m < 16; m <<= 1) ss += __shfl_xor(ss, m, 64);
    sums[r] = ss;
  }
#pragma unroll
  for (int r = 0; r < 4; r++) {
    int tq = tq0 + r;
    float rstd = rsqrtf(sums[r] * (1.0f / 64.0f) + 1e-6f);
#pragma unroll
    for (int n = 0; n < 4; n++) {
      int d = n * 16 + lr;
      float gv = QKVG[(size_t)tq * 8192 + 6144 + h * 64 + d];
      float sg = gv / (1.0f + __expf(-gv));
      float val = o[n][r] * rstd * sg;
      z[(size_t)tq * HIDDEN + h * 64 + d] = f2bf(val);
    }
  }
}

// ---------------- launch ----------------
extern "C" void kernel_launch(void* const* d_in, const int* in_sizes, int n_in,
                              void* d_out, int out_size, void* d_ws, size_t ws_size,
                              hipStream_t stream) {
  const float* hidden = (const float*)d_in[0];
  const float* Wq = (const float*)d_in[1];
  const float* Wk = (const float*)d_in[2];
  const float* Wv = (const float*)d_in[3];
  const float* Wg = (const float*)d_in[4];
  const float* Wgk = (const float*)d_in[5];
  const float* Wo = (const float*)d_in[6];
  float* out = (float*)d_out;
  char* ws = (char*)d_ws;

  const size_t NELEM = (size_t)TT * HIDDEN;            // 4M
  short* XbZ  = (short*)(ws + 0);                      // 8MB  (Xb, later reused as z)
  short* Wb   = (short*)(ws + 8388608);                // 32MB (packed Wq|Wk|Wv|Wg)
  short* Wob  = (short*)(ws + 41943040);               // 8MB
  float* QKVG = (float*)(ws + 50331648);               // 64MB
  short* qbuf = (short*)(ws + 117440512);              // 8MB
  short* kbuf = (short*)(ws + 125829120);              // 8MB
  short* vtbuf= (short*)(ws + 134217728);              // 8MB
  float* gkb  = (float*)(ws + 142606336);              // 256KB
  float* Gb   = (float*)(ws + 142868480);              // 256KB
  float2* rt  = (float2*)(ws + 143130624);             // 512KB

  cast6<<<2048, 256, 0, stream>>>(hidden, Wq, Wk, Wv, Wg, Wo,
                                  XbZ, Wb + 0 * NELEM, Wb + 1 * NELEM,
                                  Wb + 2 * NELEM, Wb + 3 * NELEM, Wob);
  rope_table_kernel<<<256, 256, 0, stream>>>(rt);
  gk_kernel<<<TT, 256, 0, stream>>>(hidden, Wgk, gkb);
  cumsum_kernel<<<NH, 64, 0, stream>>>(gkb, Gb);
  gemm256<<<dim3(32, 8), 512, 0, stream>>>(XbZ, Wb, QKVG, TT, 4 * HIDDEN, HIDDEN);
  rope_post<<<dim3(32, NH), 256, 0, stream>>>(QKVG, rt, qbuf, kbuf, vtbuf);
  attn_kernel<<<dim3(32, NH), 256, 0, stream>>>(qbuf, kbuf, vtbuf, Gb, QKVG, XbZ);
  gemm_bt<<<dim3(16, 16), 256, 0, stream>>>(XbZ, Wob, out, TT, HIDDEN, HIDDEN);
}

// Round 8
// 389.017 us; speedup vs baseline: 1.1153x; 1.0141x over previous
//
#include <hip/hip_runtime.h>
#include <hip/hip_bf16.h>
#include <stdint.h>

#define TT 2048
#define NH 32
#define HD 64
#define HIDDEN 2048

typedef __attribute__((ext_vector_type(8))) short short8;
typedef __attribute__((ext_vector_type(4))) short short4v;
typedef __attribute__((ext_vector_type(4))) float f32x4;

__device__ inline short f2bf(float x) {
  __hip_bfloat16 h = __float2bfloat16(x);
  return __builtin_bit_cast(short, h);
}

__device__ inline void gload16(const void* g, void* l) {
  __builtin_amdgcn_global_load_lds(
      (const __attribute__((address_space(1))) unsigned int*)g,
      (__attribute__((address_space(3))) unsigned int*)l, 16, 0, 0);
}

// ---------------- fused fp32 -> bf16 casts (6 buffers of 4M elems) ----------
__global__ void cast6(const float* __restrict__ s0, const float* __restrict__ s1,
                      const float* __restrict__ s2, const float* __restrict__ s3,
                      const float* __restrict__ s4, const float* __restrict__ s5,
                      short* __restrict__ d0, short* __restrict__ d1,
                      short* __restrict__ d2, short* __restrict__ d3,
                      short* __restrict__ d4, short* __restrict__ d5) {
  int t0 = blockIdx.x * 256 + threadIdx.x;
  int stride = gridDim.x * 256;
  const int NG = 1 << 20;  // 4M elems / 4 per thread
#define CAST_LOOP(S, D)                                            \
  for (int g = t0; g < NG; g += stride) {                          \
    float4 v = *reinterpret_cast<const float4*>(S + (size_t)g * 4);\
    short4v o;                                                     \
    o[0] = f2bf(v.x); o[1] = f2bf(v.y);                            \
    o[2] = f2bf(v.z); o[3] = f2bf(v.w);                            \
    *reinterpret_cast<short4v*>(D + (size_t)g * 4) = o;            \
  }
  CAST_LOOP(s0, d0)
  CAST_LOOP(s1, d1)
  CAST_LOOP(s2, d2)
  CAST_LOOP(s3, d3)
  CAST_LOOP(s4, d4)
  CAST_LOOP(s5, d5)
#undef CAST_LOOP
}

// ---------------- RoPE cos/sin table: rt[t*32+i] = (cos, sin) ----------------
__global__ void rope_table_kernel(float2* __restrict__ rt) {
  int idx = blockIdx.x * 256 + threadIdx.x;  // t*32 + i
  int t = idx >> 5, i = idx & 31;
  // inv_freq = 10000^(-i/32) = exp2(-i * log2(10000)/32)
  float inv = exp2f(-(float)i * (13.287712379549449f / 32.0f));
  float f = (float)t * inv;
  float2 cs; cs.x = cosf(f); cs.y = sinf(f);
  rt[idx] = cs;
}

// ---------------- gk = log_sigmoid(hidden @ Wgk^T)/16, stored [h][t] fp32 ----
__global__ __launch_bounds__(256) void gk_kernel(const float* __restrict__ hidden,
                                                 const float* __restrict__ Wgk,
                                                 float* __restrict__ gk) {
  int t = blockIdx.x;
  __shared__ float row[HIDDEN];
  int tid = threadIdx.x;
  const float4* hr = reinterpret_cast<const float4*>(hidden + (size_t)t * HIDDEN);
#pragma unroll
  for (int i = 0; i < 2; i++) {
    float4 v = hr[tid + i * 256];
    *reinterpret_cast<float4*>(&row[(tid + i * 256) * 4]) = v;
  }
  __syncthreads();
  int w = tid >> 6, l = tid & 63;
  for (int hh = 0; hh < 8; hh++) {
    int h = w * 8 + hh;
    const float* wr = Wgk + (size_t)h * HIDDEN;
    float acc = 0.f;
#pragma unroll
    for (int i = 0; i < 32; i++) acc = fmaf(row[i * 64 + l], wr[i * 64 + l], acc);
#pragma unroll
    for (int m = 1; m < 64; m <<= 1) acc += __shfl_xor(acc, m, 64);
    if (l == 0) {
      float x = acc;
      float ls = fminf(x, 0.f) - log1pf(__expf(-fabsf(x)));
      gk[(size_t)h * TT + t] = ls * (1.0f / 16.0f);
    }
  }
}

// ---------------- per-head inclusive cumsum over t: G[h][t] ----------------
__global__ void cumsum_kernel(const float* __restrict__ gk, float* __restrict__ G) {
  int h = blockIdx.x;
  int l = threadIdx.x;  // 64 threads
  float carry = 0.f;
  for (int c = 0; c < 32; c++) {
    float x = gk[(size_t)h * TT + c * 64 + l];
#pragma unroll
    for (int ofs = 1; ofs < 64; ofs <<= 1) {
      float y = __shfl_up(x, ofs, 64);
      if (l >= ofs) x += y;
    }
    x += carry;
    G[(size_t)h * TT + c * 64 + l] = x;
    carry = __shfl(x, 63, 64);
  }
}

// ---------------- 256x256 deep-pipelined bf16 GEMM: C = A * B^T --------------
// (unchanged from round 1 — measured: dropped out of top-5)
__global__ __launch_bounds__(512, 1) void gemm256(const short* __restrict__ A,
                                                  const short* __restrict__ B,
                                                  float* __restrict__ C,
                                                  int M, int N, int K) {
  __shared__ short lds[4 * 16384];  // [slot][A:8192 | B:8192] shorts
  int tid = threadIdx.x;
  int w = tid >> 6, l = tid & 63;
  int wr = w >> 2, wc = w & 3;
  int lr = l & 15, lg = l >> 4;

  int bx = blockIdx.x, by = blockIdx.y;
  if ((gridDim.x & 7) == 0) {
    int id = by * gridDim.x + bx;
    int sx = gridDim.x >> 3;
    int xcd = id & 7, p = id >> 3;
    bx = xcd * sx + p % sx;
    by = p / sx;
  }
  size_t tm = (size_t)by * 256, tn = (size_t)bx * 256;

  int srow = l >> 2;
  int schunk = (((l & 3) ^ ((l >> 2) & 3) ^ ((l >> 4) & 3)) << 3);
  const short* pA0 = A + (size_t)(tm + w * 16 + srow) * K + schunk;
  const short* pA1 = A + (size_t)(tm + 128 + w * 16 + srow) * K + schunk;
  const short* pB0 = B + (size_t)(tn + w * 16 + srow) * K + schunk;
  const short* pB1 = B + (size_t)(tn + 128 + w * 16 + srow) * K + schunk;
  int dA0 = (0 * 128 + w * 16) * 32;
  int dA1 = (1 * 128 + w * 16) * 32;
  int dB0 = 8192 + (0 * 128 + w * 16) * 32;
  int dB1 = 8192 + (1 * 128 + w * 16) * 32;

  int rchunk = ((lg ^ ((lr & 3) ^ ((lr >> 2) & 3))) << 3);
  int baseA = (wr * 128 + lr) * 32 + rchunk;
  int baseB = (wc * 64 + lr) * 32 + rchunk;

  f32x4 acc[8][4] = {};
  int nt = K >> 5;

  for (int t = 0; t < 3; ++t) {
    short* sb = &lds[(t & 3) * 16384];
    gload16(pA0 + (size_t)t * 32, sb + dA0);
    gload16(pA1 + (size_t)t * 32, sb + dA1);
    gload16(pB0 + (size_t)t * 32, sb + dB0);
    gload16(pB1 + (size_t)t * 32, sb + dB1);
  }
  asm volatile("s_waitcnt vmcnt(8)" ::: "memory");
  __builtin_amdgcn_s_barrier();

  for (int t = 0; t < nt; ++t) {
    const short* As = &lds[(t & 3) * 16384];
    const short* Bs = As + 8192;
    int pf = t + 3;
    bool do_pf = pf < nt;
    short* pfb = &lds[(pf & 3) * 16384];

    short8 a[4], b[4];
#pragma unroll
    for (int mi = 0; mi < 4; mi++)
      a[mi] = *reinterpret_cast<const short8*>(As + baseA + mi * 512);
#pragma unroll
    for (int ni = 0; ni < 4; ni++)
      b[ni] = *reinterpret_cast<const short8*>(Bs + baseB + ni * 512);
    if (do_pf) {
      gload16(pA0 + (size_t)pf * 32, pfb + dA0);
      gload16(pA1 + (size_t)pf * 32, pfb + dA1);
    }
    __builtin_amdgcn_s_barrier();
    asm volatile("s_waitcnt lgkmcnt(0)" ::: "memory");
    __builtin_amdgcn_s_setprio(1);
#pragma unroll
    for (int mi = 0; mi < 4; mi++)
#pragma unroll
      for (int ni = 0; ni < 4; ni++)
        acc[mi][ni] = __builtin_amdgcn_mfma_f32_16x16x32_bf16(a[mi], b[ni], acc[mi][ni], 0, 0, 0);
    __builtin_amdgcn_s_setprio(0);
    __builtin_amdgcn_s_barrier();

#pragma unroll
    for (int mi = 0; mi < 4; mi++)
      a[mi] = *reinterpret_cast<const short8*>(As + baseA + (mi + 4) * 512);
    if (do_pf) {
      gload16(pB0 + (size_t)pf * 32, pfb + dB0);
      gload16(pB1 + (size_t)pf * 32, pfb + dB1);
    }
    __builtin_amdgcn_s_barrier();
    asm volatile("s_waitcnt lgkmcnt(0)" ::: "memory");
    __builtin_amdgcn_s_setprio(1);
#pragma unroll
    for (int mi = 0; mi < 4; mi++)
#pragma unroll
      for (int ni = 0; ni < 4; ni++)
        acc[mi + 4][ni] = __builtin_amdgcn_mfma_f32_16x16x32_bf16(a[mi], b[ni], acc[mi + 4][ni], 0, 0, 0);
    __builtin_amdgcn_s_setprio(0);
    asm volatile("s_waitcnt vmcnt(8)" ::: "memory");
    __builtin_amdgcn_s_barrier();
  }

#pragma unroll
  for (int mi = 0; mi < 8; mi++)
#pragma unroll
    for (int ni = 0; ni < 4; ni++)
#pragma unroll
      for (int r = 0; r < 4; r++) {
        size_t row = tm + wr * 128 + mi * 16 + lg * 4 + r;
        size_t col = tn + wc * 64 + ni * 16 + lr;
        C[row * N + col] = acc[mi][ni][r];
      }
}

// ---------------- m97-style bf16 GEMM (kept for the 2048x2048 out-proj) -----
__global__ __launch_bounds__(256) void gemm_bt(const short* __restrict__ A,
                                               const short* __restrict__ B,
                                               float* __restrict__ C,
                                               int M, int N, int K) {
  __shared__ short As[128 * 32];
  __shared__ short Bs[128 * 32];
  int tm = blockIdx.y * 128;
  int tn = blockIdx.x * 128;
  int tid = threadIdx.x;
  int w = tid >> 6, l = tid & 63;
  int wr = w >> 1, wc = w & 1;
  int srow = l >> 2;
  int scol = (l & 3) * 8;
  int lg = l >> 4, lr = l & 15;
  f32x4 acc[4][4] = {};
  for (int k0 = 0; k0 < K; k0 += 32) {
    __syncthreads();
#pragma unroll
    for (int i = 0; i < 2; i++) {
      int r = i * 64 + w * 16 + srow;
      gload16(A + (size_t)(tm + r) * K + k0 + scol, &As[(i * 64 + w * 16) * 32]);
      gload16(B + (size_t)(tn + r) * K + k0 + scol, &Bs[(i * 64 + w * 16) * 32]);
    }
    __syncthreads();
    short8 a[4], b[4];
#pragma unroll
    for (int m = 0; m < 4; m++)
      a[m] = *reinterpret_cast<const short8*>(&As[(wr * 64 + m * 16 + lr) * 32 + lg * 8]);
#pragma unroll
    for (int n = 0; n < 4; n++)
      b[n] = *reinterpret_cast<const short8*>(&Bs[(wc * 64 + n * 16 + lr) * 32 + lg * 8]);
#pragma unroll
    for (int m = 0; m < 4; m++)
#pragma unroll
      for (int n = 0; n < 4; n++)
        acc[m][n] = __builtin_amdgcn_mfma_f32_16x16x32_bf16(a[m], b[n], acc[m][n], 0, 0, 0);
  }
#pragma unroll
  for (int m = 0; m < 4; m++)
#pragma unroll
    for (int n = 0; n < 4; n++)
#pragma unroll
      for (int r = 0; r < 4; r++) {
        int row = tm + wr * 64 + m * 16 + lg * 4 + r;
        int col = tn + wc * 64 + n * 16 + lr;
        C[(size_t)row * N + col] = acc[m][n][r];
      }
}

// ---------------- RoPE post-pass + layout conversion -------------------------
__global__ __launch_bounds__(256) void rope_post(const float* __restrict__ QKVG,
                                                 const float2* __restrict__ rt,
                                                 short* __restrict__ qb,
                                                 short* __restrict__ kb,
                                                 short* __restrict__ vtb) {
  int tb = blockIdx.x, h = blockIdx.y;
  int tid = threadIdx.x;
  int p = tid & 31;
  int r0 = tid >> 5;
#pragma unroll
  for (int rr = 0; rr < 8; rr++) {
    int rloc = r0 * 8 + rr;
    int t = tb * 64 + rloc;
    float2 cs = rt[(size_t)t * 32 + p];
    float2 xq = *reinterpret_cast<const float2*>(&QKVG[(size_t)t * 8192 + h * 64 + 2 * p]);
    float r1 = xq.x * cs.x - xq.y * cs.y;
    float r2 = xq.x * cs.y + xq.y * cs.x;
    ushort2 uq; uq.x = (unsigned short)f2bf(r1); uq.y = (unsigned short)f2bf(r2);
    *reinterpret_cast<ushort2*>(&qb[((size_t)h * TT + t) * 64 + 2 * p]) = uq;
    float2 xk = *reinterpret_cast<const float2*>(&QKVG[(size_t)t * 8192 + 2048 + h * 64 + 2 * p]);
    r1 = xk.x * cs.x - xk.y * cs.y;
    r2 = xk.x * cs.y + xk.y * cs.x;
    ushort2 uk; uk.x = (unsigned short)f2bf(r1); uk.y = (unsigned short)f2bf(r2);
    *reinterpret_cast<ushort2*>(&kb[((size_t)h * TT + t) * 64 + 2 * p]) = uk;
  }
  __shared__ float vt[64][65];
  int c = tid & 63;
  int rbase = tid >> 6;
#pragma unroll
  for (int k4 = 0; k4 < 16; k4++) {
    int rloc = rbase * 16 + k4;
    vt[rloc][c] = QKVG[(size_t)(tb * 64 + rloc) * 8192 + 4096 + h * 64 + c];
  }
  __syncthreads();
#pragma unroll
  for (int k4 = 0; k4 < 16; k4++) {
    int d = rbase * 16 + k4;
    float val = vt[c][d];
    vtb[((size_t)h * HD + d) * TT + tb * 64 + c] = f2bf(val);
  }
}

// ---------------- gated-retention attention ---------------------------------
// grid (16, 32): block bx handles q-tiles {bx, 31-bx} -> uniform 33 jb-iters.
// K/V double-buffered in LDS (2 slots, counted vmcnt(4), never 0 mid-loop).
__global__ __launch_bounds__(256) void attn_kernel(const short* __restrict__ qbuf,
                                                   const short* __restrict__ kbuf,
                                                   const short* __restrict__ vtbuf,
                                                   const float* __restrict__ G,
                                                   const float* __restrict__ QKVG,
                                                   short* __restrict__ z) {
  int bx = blockIdx.x, h = blockIdx.y;
  __shared__ short Ks[2][64 * 64];   // [slot][j][d], XOR-swizzled rows
  __shared__ short Vs[2][64 * 64];   // [slot][d][j], XOR-swizzled rows
  __shared__ short Ps[4][16 * 64];
  int tid = threadIdx.x, w = tid >> 6, l = tid & 63;
  int lg = l >> 4, lr = l & 15;
  int sj = w * 8 + (l >> 3);
  const size_t hTT = (size_t)h * TT;
  const size_t hHD = (size_t)h * HD;

  for (int job = 0; job < 2; job++) {
    int qblk = job ? 31 - bx : bx;

    int tq_row = qblk * 64 + w * 16 + lr;
    short8 aq0 = *reinterpret_cast<const short8*>(&qbuf[(hTT + tq_row) * HD + lg * 8]);
    short8 aq1 = *reinterpret_cast<const short8*>(&qbuf[(hTT + tq_row) * HD + 32 + lg * 8]);

    int tq0 = qblk * 64 + w * 16 + lg * 4;
    float Gq[4];
#pragma unroll
    for (int r = 0; r < 4; r++) Gq[r] = G[hTT + tq0 + r];

    f32x4 o[4] = {};

    // prologue: stage tile 0 into slot 0 (prior job's reads sealed by its
    // final loop barrier; epilogue touches no K/V LDS)
#pragma unroll
    for (int i = 0; i < 2; i++) {
      int row = i * 32 + sj;
      int cb = ((l & 7) ^ (row & 7)) * 8;
      gload16(&kbuf[(hTT + row) * HD + cb], &Ks[0][(i * 32 + w * 8) * 64]);
      gload16(&vtbuf[(hHD + row) * TT + cb], &Vs[0][(i * 32 + w * 8) * 64]);
    }

    for (int jb = 0; jb <= qblk; jb++) {
      int slot = jb & 1;
      if (jb < qblk) {
        int nj = jb + 1, ns = slot ^ 1;
#pragma unroll
        for (int i = 0; i < 2; i++) {
          int row = i * 32 + sj;
          int cb = ((l & 7) ^ (row & 7)) * 8;
          gload16(&kbuf[(hTT + (size_t)nj * 64 + row) * HD + cb], &Ks[ns][(i * 32 + w * 8) * 64]);
          gload16(&vtbuf[(hHD + row) * TT + (size_t)nj * 64 + cb], &Vs[ns][(i * 32 + w * 8) * 64]);
        }
        asm volatile("s_waitcnt vmcnt(4)" ::: "memory");  // tile jb resident
      } else {
        asm volatile("s_waitcnt vmcnt(0)" ::: "memory");
      }
      __syncthreads();

      const char* Kp = (const char*)&Ks[slot][0];
      const char* Vp = (const char*)&Vs[slot][0];

      // S = Q K^T (16x64 per wave), decay+mask, P -> per-wave LDS strip
#pragma unroll
      for (int n = 0; n < 4; n++) {
        int j = n * 16 + lr;
        short8 bk0 = *reinterpret_cast<const short8*>(Kp + j * 128 + ((lg * 16) ^ ((j & 7) << 4)));
        short8 bk1 = *reinterpret_cast<const short8*>(Kp + j * 128 + ((64 + lg * 16) ^ ((j & 7) << 4)));
        f32x4 s = {};
        s = __builtin_amdgcn_mfma_f32_16x16x32_bf16(aq0, bk0, s, 0, 0, 0);
        s = __builtin_amdgcn_mfma_f32_16x16x32_bf16(aq1, bk1, s, 0, 0, 0);
        int tj = jb * 64 + n * 16 + lr;
        float Gk = G[hTT + tj];
#pragma unroll
        for (int r = 0; r < 4; r++) {
          int tq = tq0 + r;
          float pv = 0.f;
          if (tj <= tq) pv = __expf(Gq[r] - Gk) * 0.125f * s[r];
          int qloc = lg * 4 + r;
          int jloc = n * 16 + lr;
          int boff = qloc * 128 + ((jloc * 2) ^ ((qloc & 7) << 4));
          *reinterpret_cast<short*>((char*)&Ps[w][0] + boff) = f2bf(pv);
        }
      }

      // PV: O += P * V (per-wave LDS strip; in-wave ds ordering)
      short8 pa0 = *reinterpret_cast<const short8*>((const char*)&Ps[w][0] + lr * 128 + ((lg * 16) ^ ((lr & 7) << 4)));
      short8 pa1 = *reinterpret_cast<const short8*>((const char*)&Ps[w][0] + lr * 128 + ((64 + lg * 16) ^ ((lr & 7) << 4)));
      __builtin_amdgcn_s_setprio(1);
#pragma unroll
      for (int n = 0; n < 4; n++) {
        int d = n * 16 + lr;
        short8 bv0 = *reinterpret_cast<const short8*>(Vp + d * 128 + ((lg * 16) ^ ((d & 7) << 4)));
        short8 bv1 = *reinterpret_cast<const short8*>(Vp + d * 128 + ((64 + lg * 16) ^ ((d & 7) << 4)));
        o[n] = __builtin_amdgcn_mfma_f32_16x16x32_bf16(pa0, bv0, o[n], 0, 0, 0);
        o[n] = __builtin_amdgcn_mfma_f32_16x16x32_bf16(pa1, bv1, o[n], 0, 0, 0);
      }
      __builtin_amdgcn_s_setprio(0);
      __syncthreads();  // all reads of this slot done before it is restaged
    }

    // epilogue: RMS-norm over d=64, * silu(gate), store bf16
    float sums[4];
#pragma unroll
    for (int r = 0; r < 4; r++) {
      float ss = 0.f;
#pragma unroll
      for (int n = 0; n < 4; n++) ss += o[n][r] * o[n][r];
#pragma unroll
      for (int m = 1; m < 16; m <<= 1) ss += __shfl_xor(ss, m, 64);
      sums[r] = ss;
    }
#pragma unroll
    for (int r = 0; r < 4; r++) {
      int tq = tq0 + r;
      float rstd = rsqrtf(sums[r] * (1.0f / 64.0f) + 1e-6f);
#pragma unroll
      for (int n = 0; n < 4; n++) {
        int d = n * 16 + lr;
        float gv = QKVG[(size_t)tq * 8192 + 6144 + h * 64 + d];
        float sg = gv / (1.0f + __expf(-gv));
        float val = o[n][r] * rstd * sg;
        z[(size_t)tq * HIDDEN + h * 64 + d] = f2bf(val);
      }
    }
  }
}

// ---------------- launch ----------------
extern "C" void kernel_launch(void* const* d_in, const int* in_sizes, int n_in,
                              void* d_out, int out_size, void* d_ws, size_t ws_size,
                              hipStream_t stream) {
  const float* hidden = (const float*)d_in[0];
  const float* Wq = (const float*)d_in[1];
  const float* Wk = (const float*)d_in[2];
  const float* Wv = (const float*)d_in[3];
  const float* Wg = (const float*)d_in[4];
  const float* Wgk = (const float*)d_in[5];
  const float* Wo = (const float*)d_in[6];
  float* out = (float*)d_out;
  char* ws = (char*)d_ws;

  const size_t NELEM = (size_t)TT * HIDDEN;            // 4M
  short* XbZ  = (short*)(ws + 0);                      // 8MB  (Xb, later reused as z)
  short* Wb   = (short*)(ws + 8388608);                // 32MB (packed Wq|Wk|Wv|Wg)
  short* Wob  = (short*)(ws + 41943040);               // 8MB
  float* QKVG = (float*)(ws + 50331648);               // 64MB
  short* qbuf = (short*)(ws + 117440512);              // 8MB
  short* kbuf = (short*)(ws + 125829120);              // 8MB
  short* vtbuf= (short*)(ws + 134217728);              // 8MB
  float* gkb  = (float*)(ws + 142606336);              // 256KB
  float* Gb   = (float*)(ws + 142868480);              // 256KB
  float2* rt  = (float2*)(ws + 143130624);             // 512KB

  cast6<<<2048, 256, 0, stream>>>(hidden, Wq, Wk, Wv, Wg, Wo,
                                  XbZ, Wb + 0 * NELEM, Wb + 1 * NELEM,
                                  Wb + 2 * NELEM, Wb + 3 * NELEM, Wob);
  rope_table_kernel<<<256, 256, 0, stream>>>(rt);
  gk_kernel<<<TT, 256, 0, stream>>>(hidden, Wgk, gkb);
  cumsum_kernel<<<NH, 64, 0, stream>>>(gkb, Gb);
  gemm256<<<dim3(32, 8), 512, 0, stream>>>(XbZ, Wb, QKVG, TT, 4 * HIDDEN, HIDDEN);
  rope_post<<<dim3(32, NH), 256, 0, stream>>>(QKVG, rt, qbuf, kbuf, vtbuf);
  attn_kernel<<<dim3(16, NH), 256, 0, stream>>>(qbuf, kbuf, vtbuf, Gb, QKVG, XbZ);
  gemm_bt<<<dim3(16, 16), 256, 0, stream>>>(XbZ, Wob, out, TT, HIDDEN, HIDDEN);
}

// Round 14
// 371.651 us; speedup vs baseline: 1.1674x; 1.0467x over previous
//
#include <hip/hip_runtime.h>
#include <hip/hip_bf16.h>
#include <stdint.h>

#define TT 2048
#define NH 32
#define HD 64
#define HIDDEN 2048

typedef __attribute__((ext_vector_type(8))) short short8;
typedef __attribute__((ext_vector_type(4))) short short4v;
typedef __attribute__((ext_vector_type(4))) float f32x4;

__device__ inline short f2bf(float x) {
  __hip_bfloat16 h = __float2bfloat16(x);
  return __builtin_bit_cast(short, h);
}

__device__ inline void gload16(const void* g, void* l) {
  __builtin_amdgcn_global_load_lds(
      (const __attribute__((address_space(1))) unsigned int*)g,
      (__attribute__((address_space(3))) unsigned int*)l, 16, 0, 0);
}

// ---------------- fused fp32 -> bf16 casts (6 buffers of 4M elems) ----------
__global__ void cast6(const float* __restrict__ s0, const float* __restrict__ s1,
                      const float* __restrict__ s2, const float* __restrict__ s3,
                      const float* __restrict__ s4, const float* __restrict__ s5,
                      short* __restrict__ d0, short* __restrict__ d1,
                      short* __restrict__ d2, short* __restrict__ d3,
                      short* __restrict__ d4, short* __restrict__ d5) {
  int t0 = blockIdx.x * 256 + threadIdx.x;
  int stride = gridDim.x * 256;
  const int NG = 1 << 20;  // 4M elems / 4 per thread
#define CAST_LOOP(S, D)                                            \
  for (int g = t0; g < NG; g += stride) {                          \
    float4 v = *reinterpret_cast<const float4*>(S + (size_t)g * 4);\
    short4v o;                                                     \
    o[0] = f2bf(v.x); o[1] = f2bf(v.y);                            \
    o[2] = f2bf(v.z); o[3] = f2bf(v.w);                            \
    *reinterpret_cast<short4v*>(D + (size_t)g * 4) = o;            \
  }
  CAST_LOOP(s0, d0)
  CAST_LOOP(s1, d1)
  CAST_LOOP(s2, d2)
  CAST_LOOP(s3, d3)
  CAST_LOOP(s4, d4)
  CAST_LOOP(s5, d5)
#undef CAST_LOOP
}

// ---------------- RoPE cos/sin table: rt[t*32+i] = (cos, sin) ----------------
__global__ void rope_table_kernel(float2* __restrict__ rt) {
  int idx = blockIdx.x * 256 + threadIdx.x;  // t*32 + i
  int t = idx >> 5, i = idx & 31;
  // inv_freq = 10000^(-i/32) = exp2(-i * log2(10000)/32)
  float inv = exp2f(-(float)i * (13.287712379549449f / 32.0f));
  float f = (float)t * inv;
  float2 cs; cs.x = cosf(f); cs.y = sinf(f);
  rt[idx] = cs;
}

// ---------------- gk = log_sigmoid(hidden @ Wgk^T)/16, stored [h][t] fp32 ----
__global__ __launch_bounds__(256) void gk_kernel(const float* __restrict__ hidden,
                                                 const float* __restrict__ Wgk,
                                                 float* __restrict__ gk) {
  int t = blockIdx.x;
  __shared__ float row[HIDDEN];
  int tid = threadIdx.x;
  const float4* hr = reinterpret_cast<const float4*>(hidden + (size_t)t * HIDDEN);
#pragma unroll
  for (int i = 0; i < 2; i++) {
    float4 v = hr[tid + i * 256];
    *reinterpret_cast<float4*>(&row[(tid + i * 256) * 4]) = v;
  }
  __syncthreads();
  int w = tid >> 6, l = tid & 63;
  for (int hh = 0; hh < 8; hh++) {
    int h = w * 8 + hh;
    const float* wr = Wgk + (size_t)h * HIDDEN;
    float acc = 0.f;
#pragma unroll
    for (int i = 0; i < 32; i++) acc = fmaf(row[i * 64 + l], wr[i * 64 + l], acc);
#pragma unroll
    for (int m = 1; m < 64; m <<= 1) acc += __shfl_xor(acc, m, 64);
    if (l == 0) {
      float x = acc;
      float ls = fminf(x, 0.f) - log1pf(__expf(-fabsf(x)));
      gk[(size_t)h * TT + t] = ls * (1.0f / 16.0f);
    }
  }
}

// ---------------- per-head inclusive cumsum over t: G[h][t] ----------------
__global__ void cumsum_kernel(const float* __restrict__ gk, float* __restrict__ G) {
  int h = blockIdx.x;
  int l = threadIdx.x;  // 64 threads
  float carry = 0.f;
  for (int c = 0; c < 32; c++) {
    float x = gk[(size_t)h * TT + c * 64 + l];
#pragma unroll
    for (int ofs = 1; ofs < 64; ofs <<= 1) {
      float y = __shfl_up(x, ofs, 64);
      if (l >= ofs) x += y;
    }
    x += carry;
    G[(size_t)h * TT + c * 64 + l] = x;
    carry = __shfl(x, 63, 64);
  }
}

// ---------------- 256x256 deep-pipelined bf16 GEMM: C = A * B^T --------------
// (unchanged — measured: dropped out of top-5)
__global__ __launch_bounds__(512, 1) void gemm256(const short* __restrict__ A,
                                                  const short* __restrict__ B,
                                                  float* __restrict__ C,
                                                  int M, int N, int K) {
  __shared__ short lds[4 * 16384];  // [slot][A:8192 | B:8192] shorts
  int tid = threadIdx.x;
  int w = tid >> 6, l = tid & 63;
  int wr = w >> 2, wc = w & 3;
  int lr = l & 15, lg = l >> 4;

  int bx = blockIdx.x, by = blockIdx.y;
  if ((gridDim.x & 7) == 0) {
    int id = by * gridDim.x + bx;
    int sx = gridDim.x >> 3;
    int xcd = id & 7, p = id >> 3;
    bx = xcd * sx + p % sx;
    by = p / sx;
  }
  size_t tm = (size_t)by * 256, tn = (size_t)bx * 256;

  int srow = l >> 2;
  int schunk = (((l & 3) ^ ((l >> 2) & 3) ^ ((l >> 4) & 3)) << 3);
  const short* pA0 = A + (size_t)(tm + w * 16 + srow) * K + schunk;
  const short* pA1 = A + (size_t)(tm + 128 + w * 16 + srow) * K + schunk;
  const short* pB0 = B + (size_t)(tn + w * 16 + srow) * K + schunk;
  const short* pB1 = B + (size_t)(tn + 128 + w * 16 + srow) * K + schunk;
  int dA0 = (0 * 128 + w * 16) * 32;
  int dA1 = (1 * 128 + w * 16) * 32;
  int dB0 = 8192 + (0 * 128 + w * 16) * 32;
  int dB1 = 8192 + (1 * 128 + w * 16) * 32;

  int rchunk = ((lg ^ ((lr & 3) ^ ((lr >> 2) & 3))) << 3);
  int baseA = (wr * 128 + lr) * 32 + rchunk;
  int baseB = (wc * 64 + lr) * 32 + rchunk;

  f32x4 acc[8][4] = {};
  int nt = K >> 5;

  for (int t = 0; t < 3; ++t) {
    short* sb = &lds[(t & 3) * 16384];
    gload16(pA0 + (size_t)t * 32, sb + dA0);
    gload16(pA1 + (size_t)t * 32, sb + dA1);
    gload16(pB0 + (size_t)t * 32, sb + dB0);
    gload16(pB1 + (size_t)t * 32, sb + dB1);
  }
  asm volatile("s_waitcnt vmcnt(8)" ::: "memory");
  __builtin_amdgcn_s_barrier();

  for (int t = 0; t < nt; ++t) {
    const short* As = &lds[(t & 3) * 16384];
    const short* Bs = As + 8192;
    int pf = t + 3;
    bool do_pf = pf < nt;
    short* pfb = &lds[(pf & 3) * 16384];

    short8 a[4], b[4];
#pragma unroll
    for (int mi = 0; mi < 4; mi++)
      a[mi] = *reinterpret_cast<const short8*>(As + baseA + mi * 512);
#pragma unroll
    for (int ni = 0; ni < 4; ni++)
      b[ni] = *reinterpret_cast<const short8*>(Bs + baseB + ni * 512);
    if (do_pf) {
      gload16(pA0 + (size_t)pf * 32, pfb + dA0);
      gload16(pA1 + (size_t)pf * 32, pfb + dA1);
    }
    __builtin_amdgcn_s_barrier();
    asm volatile("s_waitcnt lgkmcnt(0)" ::: "memory");
    __builtin_amdgcn_s_setprio(1);
#pragma unroll
    for (int mi = 0; mi < 4; mi++)
#pragma unroll
      for (int ni = 0; ni < 4; ni++)
        acc[mi][ni] = __builtin_amdgcn_mfma_f32_16x16x32_bf16(a[mi], b[ni], acc[mi][ni], 0, 0, 0);
    __builtin_amdgcn_s_setprio(0);
    __builtin_amdgcn_s_barrier();

#pragma unroll
    for (int mi = 0; mi < 4; mi++)
      a[mi] = *reinterpret_cast<const short8*>(As + baseA + (mi + 4) * 512);
    if (do_pf) {
      gload16(pB0 + (size_t)pf * 32, pfb + dB0);
      gload16(pB1 + (size_t)pf * 32, pfb + dB1);
    }
    __builtin_amdgcn_s_barrier();
    asm volatile("s_waitcnt lgkmcnt(0)" ::: "memory");
    __builtin_amdgcn_s_setprio(1);
#pragma unroll
    for (int mi = 0; mi < 4; mi++)
#pragma unroll
      for (int ni = 0; ni < 4; ni++)
        acc[mi + 4][ni] = __builtin_amdgcn_mfma_f32_16x16x32_bf16(a[mi], b[ni], acc[mi + 4][ni], 0, 0, 0);
    __builtin_amdgcn_s_setprio(0);
    asm volatile("s_waitcnt vmcnt(8)" ::: "memory");
    __builtin_amdgcn_s_barrier();
  }

#pragma unroll
  for (int mi = 0; mi < 8; mi++)
#pragma unroll
    for (int ni = 0; ni < 4; ni++)
#pragma unroll
      for (int r = 0; r < 4; r++) {
        size_t row = tm + wr * 128 + mi * 16 + lg * 4 + r;
        size_t col = tn + wc * 64 + ni * 16 + lr;
        C[row * N + col] = acc[mi][ni][r];
      }
}

// ---------------- m97-style bf16 GEMM (kept for the 2048x2048 out-proj) -----
__global__ __launch_bounds__(256) void gemm_bt(const short* __restrict__ A,
                                               const short* __restrict__ B,
                                               float* __restrict__ C,
                                               int M, int N, int K) {
  __shared__ short As[128 * 32];
  __shared__ short Bs[128 * 32];
  int tm = blockIdx.y * 128;
  int tn = blockIdx.x * 128;
  int tid = threadIdx.x;
  int w = tid >> 6, l = tid & 63;
  int wr = w >> 1, wc = w & 1;
  int srow = l >> 2;
  int scol = (l & 3) * 8;
  int lg = l >> 4, lr = l & 15;
  f32x4 acc[4][4] = {};
  for (int k0 = 0; k0 < K; k0 += 32) {
    __syncthreads();
#pragma unroll
    for (int i = 0; i < 2; i++) {
      int r = i * 64 + w * 16 + srow;
      gload16(A + (size_t)(tm + r) * K + k0 + scol, &As[(i * 64 + w * 16) * 32]);
      gload16(B + (size_t)(tn + r) * K + k0 + scol, &Bs[(i * 64 + w * 16) * 32]);
    }
    __syncthreads();
    short8 a[4], b[4];
#pragma unroll
    for (int m = 0; m < 4; m++)
      a[m] = *reinterpret_cast<const short8*>(&As[(wr * 64 + m * 16 + lr) * 32 + lg * 8]);
#pragma unroll
    for (int n = 0; n < 4; n++)
      b[n] = *reinterpret_cast<const short8*>(&Bs[(wc * 64 + n * 16 + lr) * 32 + lg * 8]);
#pragma unroll
    for (int m = 0; m < 4; m++)
#pragma unroll
      for (int n = 0; n < 4; n++)
        acc[m][n] = __builtin_amdgcn_mfma_f32_16x16x32_bf16(a[m], b[n], acc[m][n], 0, 0, 0);
  }
#pragma unroll
  for (int m = 0; m < 4; m++)
#pragma unroll
    for (int n = 0; n < 4; n++)
#pragma unroll
      for (int r = 0; r < 4; r++) {
        int row = tm + wr * 64 + m * 16 + lg * 4 + r;
        int col = tn + wc * 64 + n * 16 + lr;
        C[(size_t)row * N + col] = acc[m][n][r];
      }
}

// ---------------- RoPE post-pass + layout conversion -------------------------
__global__ __launch_bounds__(256) void rope_post(const float* __restrict__ QKVG,
                                                 const float2* __restrict__ rt,
                                                 short* __restrict__ qb,
                                                 short* __restrict__ kb,
                                                 short* __restrict__ vtb) {
  int tb = blockIdx.x, h = blockIdx.y;
  int tid = threadIdx.x;
  int p = tid & 31;
  int r0 = tid >> 5;
#pragma unroll
  for (int rr = 0; rr < 8; rr++) {
    int rloc = r0 * 8 + rr;
    int t = tb * 64 + rloc;
    float2 cs = rt[(size_t)t * 32 + p];
    float2 xq = *reinterpret_cast<const float2*>(&QKVG[(size_t)t * 8192 + h * 64 + 2 * p]);
    float r1 = xq.x * cs.x - xq.y * cs.y;
    float r2 = xq.x * cs.y + xq.y * cs.x;
    ushort2 uq; uq.x = (unsigned short)f2bf(r1); uq.y = (unsigned short)f2bf(r2);
    *reinterpret_cast<ushort2*>(&qb[((size_t)h * TT + t) * 64 + 2 * p]) = uq;
    float2 xk = *reinterpret_cast<const float2*>(&QKVG[(size_t)t * 8192 + 2048 + h * 64 + 2 * p]);
    r1 = xk.x * cs.x - xk.y * cs.y;
    r2 = xk.x * cs.y + xk.y * cs.x;
    ushort2 uk; uk.x = (unsigned short)f2bf(r1); uk.y = (unsigned short)f2bf(r2);
    *reinterpret_cast<ushort2*>(&kb[((size_t)h * TT + t) * 64 + 2 * p]) = uk;
  }
  __shared__ float vt[64][65];
  int c = tid & 63;
  int rbase = tid >> 6;
#pragma unroll
  for (int k4 = 0; k4 < 16; k4++) {
    int rloc = rbase * 16 + k4;
    vt[rloc][c] = QKVG[(size_t)(tb * 64 + rloc) * 8192 + 4096 + h * 64 + c];
  }
  __syncthreads();
#pragma unroll
  for (int k4 = 0; k4 < 16; k4++) {
    int d = rbase * 16 + k4;
    float val = vt[c][d];
    vtb[((size_t)h * HD + d) * TT + tb * 64 + c] = f2bf(val);
  }
}

// ---------------- gated-retention attention ---------------------------------
// grid (16, 32), remapped: id = by*16+bx; h = id&31 (=> id%8 == h%8 -> all 16
// blocks of a head share an XCD L2); bx = id>>5 pairs q-tiles {bx, 31-bx}.
// Swapped QK^T: S^T = mfma(K, Q) -> each lane holds 4 row-contiguous P values
// (q=lr, j=n*16+lg*4+r) -> packed ds_write_b64; Gq scalar, Gk float4.
__global__ __launch_bounds__(256) void attn_kernel(const short* __restrict__ qbuf,
                                                   const short* __restrict__ kbuf,
                                                   const short* __restrict__ vtbuf,
                                                   const float* __restrict__ G,
                                                   const float* __restrict__ QKVG,
                                                   short* __restrict__ z) {
  int id = blockIdx.y * 16 + blockIdx.x;
  int h = id & 31;
  int bx = id >> 5;
  __shared__ short Ks[2][64 * 64];   // [slot][j][d], XOR-swizzled rows
  __shared__ short Vs[2][64 * 64];   // [slot][d][j], XOR-swizzled rows
  __shared__ short Ps[4][16 * 64];
  int tid = threadIdx.x, w = tid >> 6, l = tid & 63;
  int lg = l >> 4, lr = l & 15;
  int sj = w * 8 + (l >> 3);
  const size_t hTT = (size_t)h * TT;
  const size_t hHD = (size_t)h * HD;

  for (int job = 0; job < 2; job++) {
    int qblk = job ? 31 - bx : bx;

    int tq_row = qblk * 64 + w * 16 + lr;
    short8 aq0 = *reinterpret_cast<const short8*>(&qbuf[(hTT + tq_row) * HD + lg * 8]);
    short8 aq1 = *reinterpret_cast<const short8*>(&qbuf[(hTT + tq_row) * HD + 32 + lg * 8]);

    float Gqs = G[hTT + tq_row];         // per-lane scalar (q = tq_row)
    int tq0 = qblk * 64 + w * 16 + lg * 4;  // epilogue rows

    f32x4 o[4] = {};

    // prologue: stage tile 0 into slot 0 (prior job's reads sealed by its
    // final loop barrier; epilogue touches no K/V LDS)
#pragma unroll
    for (int i = 0; i < 2; i++) {
      int row = i * 32 + sj;
      int cb = ((l & 7) ^ (row & 7)) * 8;
      gload16(&kbuf[(hTT + row) * HD + cb], &Ks[0][(i * 32 + w * 8) * 64]);
      gload16(&vtbuf[(hHD + row) * TT + cb], &Vs[0][(i * 32 + w * 8) * 64]);
    }

    for (int jb = 0; jb <= qblk; jb++) {
      int slot = jb & 1;
      if (jb < qblk) {
        int nj = jb + 1, ns = slot ^ 1;
#pragma unroll
        for (int i = 0; i < 2; i++) {
          int row = i * 32 + sj;
          int cb = ((l & 7) ^ (row & 7)) * 8;
          gload16(&kbuf[(hTT + (size_t)nj * 64 + row) * HD + cb], &Ks[ns][(i * 32 + w * 8) * 64]);
          gload16(&vtbuf[(hHD + row) * TT + (size_t)nj * 64 + cb], &Vs[ns][(i * 32 + w * 8) * 64]);
        }
        asm volatile("s_waitcnt vmcnt(4)" ::: "memory");  // tile jb resident
      } else {
        asm volatile("s_waitcnt vmcnt(0)" ::: "memory");
      }
      __syncthreads();

      const char* Kp = (const char*)&Ks[slot][0];
      const char* Vp = (const char*)&Vs[slot][0];

      // S^T = K Q^T (per wave 64j x 16q), decay+mask, packed P -> LDS strip
#pragma unroll
      for (int n = 0; n < 4; n++) {
        int j = n * 16 + lr;
        short8 bk0 = *reinterpret_cast<const short8*>(Kp + j * 128 + ((lg * 16) ^ ((j & 7) << 4)));
        short8 bk1 = *reinterpret_cast<const short8*>(Kp + j * 128 + ((64 + lg * 16) ^ ((j & 7) << 4)));
        f32x4 s = {};
        s = __builtin_amdgcn_mfma_f32_16x16x32_bf16(bk0, aq0, s, 0, 0, 0);
        s = __builtin_amdgcn_mfma_f32_16x16x32_bf16(bk1, aq1, s, 0, 0, 0);
        f32x4 Gk4 = *reinterpret_cast<const f32x4*>(&G[hTT + (size_t)jb * 64 + n * 16 + lg * 4]);
        short4v pw;
#pragma unroll
        for (int r = 0; r < 4; r++) {
          int tj = jb * 64 + n * 16 + lg * 4 + r;
          float pv = 0.f;
          if (tj <= tq_row) pv = __expf(Gqs - Gk4[r]) * 0.125f * s[r];
          pw[r] = f2bf(pv);
        }
        int boff = lr * 128 + n * 32 + lg * 8;
        *reinterpret_cast<short4v*>((char*)&Ps[w][0] + (boff ^ ((lr & 7) << 4))) = pw;
      }

      // PV: O += P * V (per-wave LDS strip; in-wave ds ordering)
      short8 pa0 = *reinterpret_cast<const short8*>((const char*)&Ps[w][0] + lr * 128 + ((lg * 16) ^ ((lr & 7) << 4)));
      short8 pa1 = *reinterpret_cast<const short8*>((const char*)&Ps[w][0] + lr * 128 + ((64 + lg * 16) ^ ((lr & 7) << 4)));
      __builtin_amdgcn_s_setprio(1);
#pragma unroll
      for (int n = 0; n < 4; n++) {
        int d = n * 16 + lr;
        short8 bv0 = *reinterpret_cast<const short8*>(Vp + d * 128 + ((lg * 16) ^ ((d & 7) << 4)));
        short8 bv1 = *reinterpret_cast<const short8*>(Vp + d * 128 + ((64 + lg * 16) ^ ((d & 7) << 4)));
        o[n] = __builtin_amdgcn_mfma_f32_16x16x32_bf16(pa0, bv0, o[n], 0, 0, 0);
        o[n] = __builtin_amdgcn_mfma_f32_16x16x32_bf16(pa1, bv1, o[n], 0, 0, 0);
      }
      __builtin_amdgcn_s_setprio(0);
      __syncthreads();  // all reads of this slot done before it is restaged
    }

    // epilogue: RMS-norm over d=64, * silu(gate), store bf16
    float sums[4];
#pragma unroll
    for (int r = 0; r < 4; r++) {
      float ss = 0.f;
#pragma unroll
      for (int n = 0; n < 4; n++) ss += o[n][r] * o[n][r];
#pragma unroll
      for (int m = 1; m < 16; m <<= 1) ss += __shfl_xor(ss, m, 64);
      sums[r] = ss;
    }
#pragma unroll
    for (int r = 0; r < 4; r++) {
      int tq = tq0 + r;
      float rstd = rsqrtf(sums[r] * (1.0f / 64.0f) + 1e-6f);
#pragma unroll
      for (int n = 0; n < 4; n++) {
        int d = n * 16 + lr;
        float gv = QKVG[(size_t)tq * 8192 + 6144 + h * 64 + d];
        float sg = gv / (1.0f + __expf(-gv));
        float val = o[n][r] * rstd * sg;
        z[(size_t)tq * HIDDEN + h * 64 + d] = f2bf(val);
      }
    }
  }
}

// ---------------- launch ----------------
extern "C" void kernel_launch(void* const* d_in, const int* in_sizes, int n_in,
                              void* d_out, int out_size, void* d_ws, size_t ws_size,
                              hipStream_t stream) {
  const float* hidden = (const float*)d_in[0];
  const float* Wq = (const float*)d_in[1];
  const float* Wk = (const float*)d_in[2];
  const float* Wv = (const float*)d_in[3];
  const float* Wg = (const float*)d_in[4];
  const float* Wgk = (const float*)d_in[5];
  const float* Wo = (const float*)d_in[6];
  float* out = (float*)d_out;
  char* ws = (char*)d_ws;

  const size_t NELEM = (size_t)TT * HIDDEN;            // 4M
  short* XbZ  = (short*)(ws + 0);                      // 8MB  (Xb, later reused as z)
  short* Wb   = (short*)(ws + 8388608);                // 32MB (packed Wq|Wk|Wv|Wg)
  short* Wob  = (short*)(ws + 41943040);               // 8MB
  float* QKVG = (float*)(ws + 50331648);               // 64MB
  short* qbuf = (short*)(ws + 117440512);              // 8MB
  short* kbuf = (short*)(ws + 125829120);              // 8MB
  short* vtbuf= (short*)(ws + 134217728);              // 8MB
  float* gkb  = (float*)(ws + 142606336);              // 256KB
  float* Gb   = (float*)(ws + 142868480);              // 256KB
  float2* rt  = (float2*)(ws + 143130624);             // 512KB

  cast6<<<2048, 256, 0, stream>>>(hidden, Wq, Wk, Wv, Wg, Wo,
                                  XbZ, Wb + 0 * NELEM, Wb + 1 * NELEM,
                                  Wb + 2 * NELEM, Wb + 3 * NELEM, Wob);
  rope_table_kernel<<<256, 256, 0, stream>>>(rt);
  gk_kernel<<<TT, 256, 0, stream>>>(hidden, Wgk, gkb);
  cumsum_kernel<<<NH, 64, 0, stream>>>(gkb, Gb);
  gemm256<<<dim3(32, 8), 512, 0, stream>>>(XbZ, Wb, QKVG, TT, 4 * HIDDEN, HIDDEN);
  rope_post<<<dim3(32, NH), 256, 0, stream>>>(QKVG, rt, qbuf, kbuf, vtbuf);
  attn_kernel<<<dim3(16, NH), 256, 0, stream>>>(qbuf, kbuf, vtbuf, Gb, QKVG, XbZ);
  gemm_bt<<<dim3(16, 16), 256, 0, stream>>>(XbZ, Wob, out, TT, HIDDEN, HIDDEN);
}